// Round 1
// baseline (1767.896 us; speedup 1.0000x reference)
//
#include <hip/hip_runtime.h>
#include <cstdint>

#define NBOX 12288
#define NWORDS 192
#define POS_THRESH 0.15f
#define NMS_THRESH 0.7f

// ---------------- Kernel 1: 3x3 conv 1024->512 + bias + ReLU ----------------
// grid 512: nb = bid&7 (N-slab of 64, XCD-local), y = bid>>3 (image row).
// Tile M=64 (one row, x=0..63) x N=64, BK=32, 256 threads, 4x4 micro-tile.
__global__ __launch_bounds__(256) void conv3x3_relu(
    const float* __restrict__ X, const float* __restrict__ Wc,
    const float* __restrict__ Bc, float* __restrict__ Y)
{
  __shared__ float As[32][64];
  __shared__ float Bs[32][64];
  const int bid = blockIdx.x;
  const int nb = bid & 7;
  const int y  = bid >> 3;
  const int t  = threadIdx.x;
  const int am  = t & 63, akq = t >> 6;      // A loader: position, k-quarter
  const int bk  = t >> 3, bn  = (t & 7) * 8; // B loader: k-row, n-segment
  const int tm  = t & 15, tn  = t >> 4;      // compute: 16x16 thread grid

  float acc[4][4];
  #pragma unroll
  for (int i = 0; i < 4; ++i)
    #pragma unroll
    for (int j = 0; j < 4; ++j) acc[i][j] = 0.f;

  for (int tap = 0; tap < 9; ++tap) {
    const int dy = tap / 3 - 1;
    const int dx = tap % 3 - 1;
    const int yy = y + dy;
    const int xx = am + dx;
    const bool aok = (yy >= 0) && (yy < 64) && (xx >= 0) && (xx < 64);
    const float* ap = X + ((yy * 64 + xx) * 1024 + akq * 8);
    const float* bp = Wc + ((tap * 1024 + bk) * 512 + nb * 64 + bn);
    for (int kb = 0; kb < 32; ++kb) {
      float4 a0 = {0.f,0.f,0.f,0.f}, a1 = {0.f,0.f,0.f,0.f};
      if (aok) {
        a0 = *(const float4*)(ap);
        a1 = *(const float4*)(ap + 4);
      }
      const float4 b0 = *(const float4*)(bp);
      const float4 b1 = *(const float4*)(bp + 4);
      __syncthreads();  // previous iteration's readers done
      const int k0 = akq * 8;
      As[k0+0][am] = a0.x; As[k0+1][am] = a0.y; As[k0+2][am] = a0.z; As[k0+3][am] = a0.w;
      As[k0+4][am] = a1.x; As[k0+5][am] = a1.y; As[k0+6][am] = a1.z; As[k0+7][am] = a1.w;
      *(float4*)&Bs[bk][bn]     = b0;
      *(float4*)&Bs[bk][bn + 4] = b1;
      __syncthreads();
      #pragma unroll
      for (int k = 0; k < 32; ++k) {
        const float4 av = *(const float4*)&As[k][tm * 4];
        const float4 bv = *(const float4*)&Bs[k][tn * 4];
        const float af[4] = {av.x, av.y, av.z, av.w};
        const float bf[4] = {bv.x, bv.y, bv.z, bv.w};
        #pragma unroll
        for (int i = 0; i < 4; ++i)
          #pragma unroll
          for (int j = 0; j < 4; ++j)
            acc[i][j] = fmaf(af[i], bf[j], acc[i][j]);
      }
      ap += 32;        // next 32 channels
      bp += 32 * 512;  // next 32 k-rows
    }
  }

  const int n0 = nb * 64 + tn * 4;
  const float4 bias = *(const float4*)&Bc[n0];
  #pragma unroll
  for (int i = 0; i < 4; ++i) {
    const int m = tm * 4 + i;
    float4 v;
    v.x = fmaxf(acc[i][0] + bias.x, 0.f);
    v.y = fmaxf(acc[i][1] + bias.y, 0.f);
    v.z = fmaxf(acc[i][2] + bias.z, 0.f);
    v.w = fmaxf(acc[i][3] + bias.w, 0.f);
    *(float4*)&Y[(y * 64 + m) * 512 + n0] = v;
  }
}

// ---------------- Kernel 2: 1x1 heads + softmax(6) + decode ----------------
// grid 4096 (one block = one wave = one position).
__global__ __launch_bounds__(64) void heads_decode(
    const float* __restrict__ Yx, const float* __restrict__ Wcls,
    const float* __restrict__ bcls, const float* __restrict__ Wreg,
    const float* __restrict__ breg, float* __restrict__ boxes,
    float* __restrict__ scores)
{
  __shared__ float xs[512];
  const int pos = blockIdx.x;
  const int l = threadIdx.x;
  const float* xrow = Yx + (size_t)pos * 512;
  *(float4*)&xs[l * 8]     = *(const float4*)&xrow[l * 8];
  *(float4*)&xs[l * 8 + 4] = *(const float4*)&xrow[l * 8 + 4];
  __syncthreads();

  // lanes 0..5 -> cls logits, 6..17 -> reg outputs, others idle.
  const float* wp;
  int oc;
  float bini;
  if (l < 6)       { wp = Wcls + l;       oc = 6;  bini = bcls[l]; }
  else if (l < 18) { wp = Wreg + (l - 6); oc = 12; bini = breg[l - 6]; }
  else             { wp = Wcls;           oc = 0;  bini = 0.f; }
  float acc = bini;
  const float* p = wp;
  #pragma unroll 4
  for (int c = 0; c < 512; ++c) { acc = fmaf(xs[c], *p, acc); p += oc; }

  // gather 6 logits + 4 deltas for anchor a (lanes 0..2 write)
  const float l0 = __shfl(acc, 0), l1 = __shfl(acc, 1), l2 = __shfl(acc, 2);
  const float l3 = __shfl(acc, 3), l4 = __shfl(acc, 4), l5 = __shfl(acc, 5);
  const int a = (l < 3) ? l : 0;
  const float d0 = __shfl(acc, 6 + a * 4 + 0);
  const float d1 = __shfl(acc, 6 + a * 4 + 1);
  const float d2 = __shfl(acc, 6 + a * 4 + 2);
  const float d3 = __shfl(acc, 6 + a * 4 + 3);

  // softmax over all 6 channels (axis=-1), score = component 2a+1
  const float mx = fmaxf(fmaxf(fmaxf(l0, l1), fmaxf(l2, l3)), fmaxf(l4, l5));
  const float e0 = expf(l0 - mx), e1 = expf(l1 - mx), e2 = expf(l2 - mx);
  const float e3 = expf(l3 - mx), e4 = expf(l4 - mx), e5 = expf(l5 - mx);
  const float den = ((((e0 + e1) + e2) + e3) + e4) + e5;
  const float esel = (a == 0) ? e1 : ((a == 1) ? e3 : e5);
  const float sc = esel / den;

  // anchors (match np rounding)
  const int px = pos & 63, py = pos >> 6;
  const float cx = (px + 0.5f) * 16.0f;
  const float cy = (py + 0.5f) * 16.0f;
  const float ratio = (a == 0) ? 0.5f : ((a == 1) ? 1.0f : 2.0f);
  const float sq = sqrtf(ratio);
  const float wsz = 128.0f * sq;
  const float hsz = 128.0f / sq;
  const float a0 = cx - wsz * 0.5f;
  const float a1 = cy - hsz * 0.5f;
  const float a2 = cx + wsz * 0.5f;
  const float a3 = cy + hsz * 0.5f;
  const float w = a2 - a0, h = a3 - a1;
  const float xc = __fadd_rn(__fmul_rn(__fadd_rn(a0, a2), 0.5f), __fmul_rn(d0, w));
  const float yc = __fadd_rn(__fmul_rn(__fadd_rn(a1, a3), 0.5f), __fmul_rn(d1, h));
  const float nw = __fmul_rn(w, expf(d2));
  const float nh = __fmul_rn(h, expf(d3));
  float4 box;
  box.x = __fsub_rn(xc, __fmul_rn(nw, 0.5f));
  box.y = __fsub_rn(yc, __fmul_rn(nh, 0.5f));
  box.z = __fadd_rn(xc, __fmul_rn(nw, 0.5f));
  box.w = __fadd_rn(yc, __fmul_rn(nh, 0.5f));

  if (l < 3) {
    const int idx = pos * 3 + a;
    *(float4*)&boxes[idx * 4] = box;
    scores[idx] = sc;
  }
}

// ---------------- Kernel 3: suppression bit-matrix (transposed) ----------------
// grid (192 words x 192 row-chunks); block 256 = 4 waves x 16 rows each.
// maskT[w * NBOX + i] = 64 bits over columns j = w*64..w*64+63: IoU(i,j)>0.7 && j>i
__global__ __launch_bounds__(256) void build_mask(
    const float* __restrict__ boxes, unsigned long long* __restrict__ maskT)
{
  const int w  = blockIdx.x;
  const int ci = blockIdx.y;
  if (w < ci) return;
  __shared__ float4 rb[64];
  const int t = threadIdx.x;
  const int lane = t & 63, wid = t >> 6;
  if (t < 64) rb[t] = *(const float4*)&boxes[(ci * 64 + t) * 4];
  const float4 cb = *(const float4*)&boxes[(w * 64 + lane) * 4];
  const float careaa = __fmul_rn(cb.z - cb.x, cb.w - cb.y);
  const int jglob = w * 64 + lane;
  __syncthreads();
  for (int rr = 0; rr < 16; ++rr) {
    const int r = wid * 16 + rr;
    const int row = ci * 64 + r;
    const float4 rx = rb[r];
    const float ra = __fmul_rn(rx.z - rx.x, rx.w - rx.y);
    const float xx1 = fmaxf(rx.x, cb.x);
    const float yy1 = fmaxf(rx.y, cb.y);
    const float xx2 = fminf(rx.z, cb.z);
    const float yy2 = fminf(rx.w, cb.w);
    const float iw = fmaxf(__fsub_rn(xx2, xx1), 0.f);
    const float ih = fmaxf(__fsub_rn(yy2, yy1), 0.f);
    const float inter = __fmul_rn(iw, ih);
    const float den = __fadd_rn(__fsub_rn(__fadd_rn(ra, careaa), inter), 1e-9f);
    const float iou = __fdiv_rn(inter, den);
    const bool bit = (iou > NMS_THRESH) && (jglob > row);
    const unsigned long long word = __ballot(bit ? 1 : 0);
    if (lane == 0) maskT[(size_t)w * NBOX + row] = word;
  }
}

// ---------------- Kernel 4: sequential greedy NMS scan (single block) ----------------
__global__ __launch_bounds__(256) void nms_scan(
    const float* __restrict__ scores, const unsigned long long* __restrict__ maskT,
    unsigned long long* __restrict__ aliveOut)
{
  __shared__ unsigned long long alive[NWORDS];
  const int t = threadIdx.x;
  if (t < NWORDS) {
    unsigned long long wbits = 0ull;
    const float* sp = scores + t * 64;
    for (int b = 0; b < 64; ++b)
      if (sp[b] > POS_THRESH) wbits |= (1ull << b);
    alive[t] = wbits;
  }
  __syncthreads();
  const int lane = t & 63, wid = t >> 6;
  for (int c = 0; c < NWORDS; ++c) {
    // phase A: wave 0 resolves intra-chunk greedy suppression
    if (wid == 0) {
      const unsigned long long dg = maskT[(size_t)c * NBOX + c * 64 + lane];
      unsigned long long aw = alive[c];
      for (int b = 0; b < 64; ++b) {
        const unsigned long long rbw = __shfl(dg, b);
        if ((aw >> b) & 1ull) aw &= ~rbw;
      }
      if (lane == 0) alive[c] = aw;
    }
    __syncthreads();
    // phase B: surviving rows suppress later words
    const unsigned long long aw = alive[c];
    if (aw) {
      for (int w = c + 1 + t; w < NWORDS; w += 256) {
        const unsigned long long* mp = maskT + (size_t)w * NBOX + c * 64;
        unsigned long long sup = 0ull;
        #pragma unroll
        for (int b = 0; b < 64; ++b) {
          const unsigned long long m = mp[b];
          const unsigned long long sel = 0ull - ((aw >> b) & 1ull);
          sup |= (m & sel);
        }
        alive[w] &= ~sup;
      }
    }
    __syncthreads();
  }
  if (t < NWORDS) aliveOut[t] = alive[t];
}

// ---------------- Kernel 5: masked output ----------------
__global__ __launch_bounds__(256) void write_output(
    const float* __restrict__ boxes, const unsigned long long* __restrict__ alive,
    float* __restrict__ out)
{
  const int i = blockIdx.x * 256 + threadIdx.x;
  if (i < NBOX) {
    const bool k = (alive[i >> 6] >> (i & 63)) & 1ull;
    const float4 b = *(const float4*)&boxes[i * 4];
    const float4 z = {0.f, 0.f, 0.f, 0.f};
    *(float4*)&out[i * 4] = k ? b : z;
  }
}

extern "C" void kernel_launch(void* const* d_in, const int* in_sizes, int n_in,
                              void* d_out, int out_size, void* d_ws, size_t ws_size,
                              hipStream_t stream) {
  const float* X    = (const float*)d_in[0];  // (1,64,64,1024)
  const float* Wc   = (const float*)d_in[1];  // (3,3,1024,512)
  const float* Bc   = (const float*)d_in[2];  // (512,)
  const float* Wcls = (const float*)d_in[3];  // (1,1,512,6)
  const float* bcls = (const float*)d_in[4];  // (6,)
  const float* Wreg = (const float*)d_in[5];  // (1,1,512,12)
  const float* breg = (const float*)d_in[6];  // (12,)

  char* ws = (char*)d_ws;
  float* Yx                      = (float*)(ws);             // 8,388,608 B
  float* boxes                   = (float*)(ws + 8388608);   //   196,608 B
  float* scores                  = (float*)(ws + 8585216);   //    49,152 B
  unsigned long long* aliveG     = (unsigned long long*)(ws + 8634368);  // 1,536 B
  unsigned long long* maskT      = (unsigned long long*)(ws + 8636416);  // 18,874,368 B

  conv3x3_relu<<<512, 256, 0, stream>>>(X, Wc, Bc, Yx);
  heads_decode<<<4096, 64, 0, stream>>>(Yx, Wcls, bcls, Wreg, breg, boxes, scores);
  build_mask<<<dim3(192, 192), 256, 0, stream>>>(boxes, maskT);
  nms_scan<<<1, 256, 0, stream>>>(scores, maskT, aliveG);
  write_output<<<48, 256, 0, stream>>>(boxes, aliveG, (float*)d_out);
}